// Round 8
// baseline (491.633 us; speedup 1.0000x reference)
//
#include <hip/hip_runtime.h>
#include <cstdint>
#include <cmath>

#define B_ 4
#define H_ 256
#define C_ 80
#define TX_ 256
#define TY_ 1024
#define NC_ 64                 // chunks of 16 columns
#define NEGF (-1e9f)

// output layout (floats): o_en_ex [B,H,TY] | logp [B,TX,TY] | attn [B,TX,TY] | dr [B,TX]
#define OFF_LOGP (B_*H_*TY_)
#define OFF_ATTN (OFF_LOGP + B_*TX_*TY_)
#define OFF_DR   (OFF_ATTN + B_*TX_*TY_)

// __shfl_up(x,1) as pure VALU: DPP wave_shr:1 (ctrl 0x138); lane 0 gets NEGF.
__device__ __forceinline__ float dpp_shr1_negfill_f32(float x) {
  union { float f; int i; } u, o, r;
  u.f = x; o.f = NEGF;
  r.i = __builtin_amdgcn_update_dpp(o.i, u.i, 0x138, 0xf, 0xf, false);
  return r.f;
}

// ---------------------------------------------------------------------------
// Kernel A: logp[b,x,t] = -0.5*mean_c((y-mu)^2*exp(-2 ls)) - 0.5*mean_c(ls)
// Expanded: (y-mu)^2 w = (w*y + m1)*y + w*mu^2, m1 = -2*w*mu; K = sum w*mu^2
// folded out of the t-loop.  f64 accumulate, f32 store.
// Also writes masked+transposed lpT[b,t,x] into the attn output region.
// ---------------------------------------------------------------------------
__global__ __launch_bounds__(256) void k_logp(
    const float* __restrict__ mu, const float* __restrict__ ls,
    const float* __restrict__ y, const int* __restrict__ xlp,
    const int* __restrict__ ylp, float* __restrict__ logp_out,
    float* __restrict__ lpT)
{
  const int b  = blockIdx.y;
  const int x0 = blockIdx.x * 4;     // 4 x's per block
  const int tid = threadIdx.x;
  __shared__ double s_w[4][C_];
  __shared__ double s_m1[4][C_];
  __shared__ double s_wm2[4][C_];
  __shared__ double s_lsv[4][C_];
  __shared__ double s_K[4];
  __shared__ double s_t0[4];
  __shared__ float tile[TY_][4];     // [t][xi] transposed tile, 16 KB
  for (int i = tid; i < 4 * C_; i += 256) {
    int xi = i / C_, c = i - xi * C_;
    double m = (double)mu[(b * C_ + c) * TX_ + x0 + xi];
    double l = (double)ls[(b * C_ + c) * TX_ + x0 + xi];
    double w = exp(-2.0 * l);
    s_w[xi][c]   = w;
    s_m1[xi][c]  = -2.0 * w * m;
    s_wm2[xi][c] = w * m * m;
    s_lsv[xi][c] = l;
  }
  __syncthreads();
  {
    int xi = tid >> 6, cc = tid & 63;
    double kp = (cc < C_) ? s_wm2[xi][cc] : 0.0;
    double tp = (cc < C_) ? s_lsv[xi][cc] : 0.0;
    if (cc + 64 < C_) { kp += s_wm2[xi][cc + 64]; tp += s_lsv[xi][cc + 64]; }
#pragma unroll
    for (int off = 32; off; off >>= 1) {
      kp += __shfl_down(kp, off);
      tp += __shfl_down(tp, off);
    }
    if (cc == 0) { s_K[xi] = kp; s_t0[xi] = -0.5 * (tp * (1.0 / C_)); }
  }
  __syncthreads();

  const int t0 = tid * 4;
  double acc[4][4];
#pragma unroll
  for (int xi = 0; xi < 4; ++xi)
#pragma unroll
    for (int k = 0; k < 4; ++k) acc[xi][k] = 0.0;

  const float4* yp = (const float4*)(y + (size_t)b * C_ * TY_) + tid;
#pragma unroll 4
  for (int c = 0; c < C_; ++c) {
    float4 yv = yp[c * (TY_ / 4)];
    double y0 = yv.x, y1 = yv.y, y2 = yv.z, y3 = yv.w;
#pragma unroll
    for (int xi = 0; xi < 4; ++xi) {
      double w = s_w[xi][c], m1 = s_m1[xi][c];
      double u0 = fma(w, y0, m1), u1 = fma(w, y1, m1);
      double u2 = fma(w, y2, m1), u3 = fma(w, y3, m1);
      acc[xi][0] = fma(u0, y0, acc[xi][0]);
      acc[xi][1] = fma(u1, y1, acc[xi][1]);
      acc[xi][2] = fma(u2, y2, acc[xi][2]);
      acc[xi][3] = fma(u3, y3, acc[xi][3]);
    }
  }

  const int xlen = xlp[b], ylen = ylp[b];
#pragma unroll
  for (int xi = 0; xi < 4; ++xi) {
    int x = x0 + xi;
    double c0 = s_t0[xi], K = s_K[xi];
    float r[4];
#pragma unroll
    for (int k = 0; k < 4; ++k)
      r[k] = (float)((acc[xi][k] + K) * (-0.5 / C_) + c0);
    *(float4*)&logp_out[((size_t)(b * TX_ + x)) * TY_ + t0] =
        make_float4(r[0], r[1], r[2], r[3]);
    bool xm = x < xlen;
#pragma unroll
    for (int k = 0; k < 4; ++k)
      tile[t0 + k][xi] = (xm && (t0 + k) < ylen) ? r[k] : NEGF;
  }
  __syncthreads();

  float* dst = lpT + (size_t)b * TY_ * TX_ + x0;
  const float4* tp = (const float4*)tile;
#pragma unroll
  for (int k = 0; k < 4; ++k) {
    int t = tid + 256 * k;           // consecutive lanes -> consecutive t
    *(float4*)&dst[(size_t)t * TX_] = tp[t];
  }
}

// ---------------------------------------------------------------------------
// Kernel B: Viterbi DP fwd + backtrack. 2 waves/block.
// The barrier is the scheduling fence: consumer's ds_reads for chunk c+1 sit
// AFTER the consumption of chunk c and BEFORE __syncthreads(), so the
// compiler cannot sink reads to uses (illegal across s_barrier) — chunk
// registers are forced live across the barrier, one lgkm drain per 16 cols
// (R1-R7 all degenerated to one exposed latency per column because within a
// basic block the scheduler pairs each load with its use).
// Phase c: consumer consumes chunk c (regs), reads chunk c+1 from
// buf[(c+1)&1]; producer ds_writes chunk c+2 (loaded last phase) into
// buf[c&1], issues global loads for chunk c+3.  Barrier.
// LDS 64KB: ring [0,8192) floats (2 bufs), bits [8192,16384), dur aliases ring.
// ---------------------------------------------------------------------------
__global__ __launch_bounds__(128, 1) void k_dp(
    const float* __restrict__ lpT, const int* __restrict__ xlp,
    const int* __restrict__ ylp, float* __restrict__ dr_out,
    int* __restrict__ cum_ws, int* __restrict__ xt_ws)
{
  const int b = blockIdx.x;
  const int lane = threadIdx.x & 63;
  const int wid  = threadIdx.x >> 6;
  __shared__ uint32_t smem[16384];           // 64 KB
  float* ring = (float*)smem;                // [0,8192) floats: buf0|buf1
  uint32_t* bits = smem + 8192;              // [w*256 + x]

  const float4* src = (const float4*)(lpT + (size_t)b * TY_ * TX_) + lane;
  // column t lives at src[t*64]

  float v0 = (lane == 0) ? 0.0f : NEGF, v1 = NEGF, v2 = NEGF, v3 = NEGF;
  float sh = NEGF;
  uint32_t b0 = 0, b1 = 0, b2 = 0, b3 = 0;
  float4 RA[16], RB[16], P[16];

#define DPSTEP(CL, BIT)                                                      \
  {                                                                          \
    const float vs0 = sh;                                                    \
    if (vs0 > v0) b0 |= (BIT);                                               \
    if (v0 > v1)  b1 |= (BIT);                                               \
    if (v1 > v2)  b2 |= (BIT);                                               \
    if (v2 > v3)  b3 |= (BIT);                                               \
    float nv3 = (CL).w + fmaxf(v3, v2);                                      \
    sh = dpp_shr1_negfill_f32(nv3);                                          \
    float nv2 = (CL).z + fmaxf(v2, v1);                                      \
    float nv1 = (CL).y + fmaxf(v1, v0);                                      \
    float nv0 = (CL).x + fmaxf(v0, vs0);                                     \
    v0 = nv0; v1 = nv1; v2 = nv2; v3 = nv3;                                  \
  }

  // ---- prologue ----
  if (wid == 1) {
#pragma unroll
    for (int i = 0; i < 16; ++i) P[i] = src[i * 64];               // chunk0
#pragma unroll
    for (int i = 0; i < 16; ++i)
      *(float4*)&ring[i * 256 + 4 * lane] = P[i];                  // -> buf0
#pragma unroll
    for (int i = 0; i < 16; ++i) P[i] = src[(16 + i) * 64];        // chunk1
  }
  __syncthreads();   // A: buf0 = chunk0
  if (wid == 0) {
#pragma unroll
    for (int i = 0; i < 16; ++i)
      RA[i] = *(const float4*)&ring[i * 256 + 4 * lane];           // chunk0
  } else {
#pragma unroll
    for (int i = 0; i < 16; ++i)
      *(float4*)&ring[4096 + i * 256 + 4 * lane] = P[i];           // -> buf1
#pragma unroll
    for (int i = 0; i < 16; ++i) P[i] = src[(32 + i) * 64];        // chunk2
  }
  __syncthreads();   // B: RA = chunk0, buf1 = chunk1, P = chunk2

  // ---- main loop: two phases per iteration (even c / odd c+1) ----
  for (int c = 0; c < NC_; c += 2) {
    if (wid == 0) {
      // phase c (even): consume chunk c from RA (bits 0..15 of word c>>1)
#pragma unroll
      for (int i = 0; i < 16; ++i) DPSTEP(RA[i], 1u << i);
      // read chunk c+1 (odd -> buf1); cannot sink past the barrier
#pragma unroll
      for (int i = 0; i < 16; ++i)
        RB[i] = *(const float4*)&ring[4096 + i * 256 + 4 * lane];
    } else {
      // write chunk c+2 (even) -> buf0; load chunk c+3 (clamped)
#pragma unroll
      for (int i = 0; i < 16; ++i)
        *(float4*)&ring[i * 256 + 4 * lane] = P[i];
      const int tl = (c + 3 < NC_ ? c + 3 : NC_ - 1) * 16;
#pragma unroll
      for (int i = 0; i < 16; ++i) P[i] = src[(tl + i) * 64];
    }
    __syncthreads();

    if (wid == 0) {
      // phase c+1 (odd): consume chunk c+1 from RB (bits 16..31), flush word
#pragma unroll
      for (int i = 0; i < 16; ++i) DPSTEP(RB[i], 1u << (16 + i));
      {
        const int w = c >> 1;        // ((c+1)*16+15)>>5
        uint4 pk; pk.x = b0; pk.y = b1; pk.z = b2; pk.w = b3;
        *(uint4*)&bits[w * 256 + 4 * lane] = pk;
        b0 = b1 = b2 = b3 = 0;
      }
      // read chunk c+2 (even -> buf0); garbage at final phase, never used
#pragma unroll
      for (int i = 0; i < 16; ++i)
        RA[i] = *(const float4*)&ring[i * 256 + 4 * lane];
    } else {
      // write chunk c+3 (odd) -> buf1; load chunk c+4 (clamped)
#pragma unroll
      for (int i = 0; i < 16; ++i)
        *(float4*)&ring[4096 + i * 256 + 4 * lane] = P[i];
      const int tl = (c + 4 < NC_ ? c + 4 : NC_ - 1) * 16;
#pragma unroll
      for (int i = 0; i < 16; ++i) P[i] = src[(tl + i) * 64];
    }
    __syncthreads();
  }
#undef DPSTEP

  // ---- backtrack (dur aliases the now-dead ring) ----
  uint32_t* dur = smem;
  for (int j = threadIdx.x; j < TX_; j += 128) dur[j] = 0;
  __syncthreads();

  const int xlen = xlp[b], ylen = ylp[b];
  if (threadIdx.x == 0) {
    int idx = xlen - 1;
    int t = ylen - 1;
    while (t >= 0) {
      if (idx == 0) { dur[0] += (uint32_t)(t + 1); break; }
      int w = t >> 5, rr = t & 31;
      uint32_t word = bits[w * 256 + idx];
      word &= (rr == 31) ? 0xffffffffu : ((1u << (rr + 1)) - 1u);
      while (word == 0 && w > 0) { --w; word = bits[w * 256 + idx]; }
      if (word == 0) { dur[idx] += (uint32_t)(t + 1); break; }
      int bitpos = 31 - __builtin_clz(word);
      int tp = (w << 5) | bitpos;        // step where diag fires -> decrement
      dur[idx] += (uint32_t)(t - tp + 1);
      --idx;
      t = tp - 1;
    }
  }
  __syncthreads();

  if (wid == 0) {
    // wave-wide inclusive scan of durations -> cum, dr, and t->x scatter map
    uint32_t d0 = dur[4 * lane], d1 = dur[4 * lane + 1];
    uint32_t d2 = dur[4 * lane + 2], d3 = dur[4 * lane + 3];
    uint32_t own = d0 + d1 + d2 + d3;
    uint32_t s = own;
#pragma unroll
    for (int off = 1; off < 64; off <<= 1) {
      uint32_t n = __shfl_up(s, off);
      if (lane >= off) s += n;
    }
    uint32_t base = s - own;
    uint32_t c0 = base + d0, c1 = c0 + d1, c2 = c1 + d2, c3 = c2 + d3;
    int x = 4 * lane;
    cum_ws[b * TX_ + x]     = (int)c0;
    cum_ws[b * TX_ + x + 1] = (int)c1;
    cum_ws[b * TX_ + x + 2] = (int)c2;
    cum_ws[b * TX_ + x + 3] = (int)c3;
    dr_out[b * TX_ + x]     = (float)d0;
    dr_out[b * TX_ + x + 1] = (float)d1;
    dr_out[b * TX_ + x + 2] = (float)d2;
    dr_out[b * TX_ + x + 3] = (float)d3;
    int* xt = xt_ws + b * TY_;
    for (uint32_t t = c0 - d0; t < c0; ++t) xt[t] = x;
    for (uint32_t t = c1 - d1; t < c1; ++t) xt[t] = x + 1;
    for (uint32_t t = c2 - d2; t < c2; ++t) xt[t] = x + 2;
    for (uint32_t t = c3 - d3; t < c3; ++t) xt[t] = x + 3;
  }
}

// ---------------------------------------------------------------------------
// Kernel C (fused epilogue): blocks [0,TX) write attn rows from cum;
// blocks [TX,TX+H) gather o_en_ex[b,h,t] = t<ylen ? en[b,h,xt[b,t]] : 0.
// ---------------------------------------------------------------------------
__global__ __launch_bounds__(256) void k_epi(
    const int* __restrict__ cum_ws, const int* __restrict__ xt_ws,
    const float* __restrict__ en, const int* __restrict__ ylp,
    float* __restrict__ attn, float* __restrict__ oen)
{
  const int b = blockIdx.y, bx = blockIdx.x, tid = threadIdx.x;
  __shared__ float row[TX_];
  if (bx < TX_) {
    const int x = bx;
    int hi = cum_ws[b * TX_ + x];
    int lo = (x > 0) ? cum_ws[b * TX_ + x - 1] : 0;
    int t0 = tid * 4;
    float4 v;
    v.x = (t0     >= lo && t0     < hi) ? 1.f : 0.f;
    v.y = (t0 + 1 >= lo && t0 + 1 < hi) ? 1.f : 0.f;
    v.z = (t0 + 2 >= lo && t0 + 2 < hi) ? 1.f : 0.f;
    v.w = (t0 + 3 >= lo && t0 + 3 < hi) ? 1.f : 0.f;
    *(float4*)&attn[((size_t)(b * TX_ + x)) * TY_ + t0] = v;
  } else {
    const int h = bx - TX_;
    row[tid] = en[((size_t)(b * H_ + h)) * TX_ + tid];
    __syncthreads();
    const int ylen = ylp[b];
    int t0 = tid * 4;
    int4 xi = *(const int4*)&xt_ws[b * TY_ + t0];
    float4 v;
    v.x = (t0     < ylen) ? row[xi.x & (TX_ - 1)] : 0.f;
    v.y = (t0 + 1 < ylen) ? row[xi.y & (TX_ - 1)] : 0.f;
    v.z = (t0 + 2 < ylen) ? row[xi.z & (TX_ - 1)] : 0.f;
    v.w = (t0 + 3 < ylen) ? row[xi.w & (TX_ - 1)] : 0.f;
    *(float4*)&oen[((size_t)(b * H_ + h)) * TY_ + t0] = v;
  }
}

extern "C" void kernel_launch(void* const* d_in, const int* in_sizes, int n_in,
                              void* d_out, int out_size, void* d_ws, size_t ws_size,
                              hipStream_t stream)
{
  const float* en = (const float*)d_in[0];
  const float* mu = (const float*)d_in[1];
  const float* ls = (const float*)d_in[2];
  const float* y  = (const float*)d_in[3];
  const int*   xl = (const int*)d_in[4];
  const int*   yl = (const int*)d_in[5];

  float* out  = (float*)d_out;
  float* oen  = out;             // [B,H,TY]
  float* logp = out + OFF_LOGP;  // [B,TX,TY]
  float* attn = out + OFF_ATTN;  // [B,TX,TY] (doubles as lpT scratch first)
  float* dr   = out + OFF_DR;    // [B,TX]

  int* cum = (int*)d_ws;               // B*TX ints
  int* xt  = cum + B_ * TX_;           // B*TY ints

  k_logp<<<dim3(TX_ / 4, B_),   256, 0, stream>>>(mu, ls, y, xl, yl, logp, attn);
  k_dp  <<<B_,                  128, 0, stream>>>(attn, xl, yl, dr, cum, xt);
  k_epi <<<dim3(TX_ + H_, B_),  256, 0, stream>>>(cum, xt, en, yl, attn, oen);
}

// Round 12
// 198.177 us; speedup vs baseline: 2.4808x; 2.4808x over previous
//
#include <hip/hip_runtime.h>
#include <cstdint>
#include <cmath>

#define B_ 4
#define H_ 256
#define C_ 80
#define TX_ 256
#define TY_ 1024
#define NC_ 64                 // chunks of 16 columns
#define NEGF (-1e9f)

// output layout (floats): o_en_ex [B,H,TY] | logp [B,TX,TY] | attn [B,TX,TY] | dr [B,TX]
#define OFF_LOGP (B_*H_*TY_)
#define OFF_ATTN (OFF_LOGP + B_*TX_*TY_)
#define OFF_DR   (OFF_ATTN + B_*TX_*TY_)

// __shfl_up(x,1) as pure VALU: DPP wave_shr:1 (ctrl 0x138); lane 0 gets NEGF.
__device__ __forceinline__ float dpp_shr1_negfill_f32(float x) {
  union { float f; int i; } u, o, r;
  u.f = x; o.f = NEGF;
  r.i = __builtin_amdgcn_update_dpp(o.i, u.i, 0x138, 0xf, 0xf, false);
  return r.f;
}

// ---------------------------------------------------------------------------
// Kernel A: logp (unchanged from R7, passing).
// ---------------------------------------------------------------------------
__global__ __launch_bounds__(256) void k_logp(
    const float* __restrict__ mu, const float* __restrict__ ls,
    const float* __restrict__ y, const int* __restrict__ xlp,
    const int* __restrict__ ylp, float* __restrict__ logp_out,
    float* __restrict__ lpT)
{
  const int b  = blockIdx.y;
  const int x0 = blockIdx.x * 4;
  const int tid = threadIdx.x;
  __shared__ double s_w[4][C_];
  __shared__ double s_m1[4][C_];
  __shared__ double s_wm2[4][C_];
  __shared__ double s_lsv[4][C_];
  __shared__ double s_K[4];
  __shared__ double s_t0[4];
  __shared__ float tile[TY_][4];
  for (int i = tid; i < 4 * C_; i += 256) {
    int xi = i / C_, c = i - xi * C_;
    double m = (double)mu[(b * C_ + c) * TX_ + x0 + xi];
    double l = (double)ls[(b * C_ + c) * TX_ + x0 + xi];
    double w = exp(-2.0 * l);
    s_w[xi][c]   = w;
    s_m1[xi][c]  = -2.0 * w * m;
    s_wm2[xi][c] = w * m * m;
    s_lsv[xi][c] = l;
  }
  __syncthreads();
  {
    int xi = tid >> 6, cc = tid & 63;
    double kp = (cc < C_) ? s_wm2[xi][cc] : 0.0;
    double tp = (cc < C_) ? s_lsv[xi][cc] : 0.0;
    if (cc + 64 < C_) { kp += s_wm2[xi][cc + 64]; tp += s_lsv[xi][cc + 64]; }
#pragma unroll
    for (int off = 32; off; off >>= 1) {
      kp += __shfl_down(kp, off);
      tp += __shfl_down(tp, off);
    }
    if (cc == 0) { s_K[xi] = kp; s_t0[xi] = -0.5 * (tp * (1.0 / C_)); }
  }
  __syncthreads();

  const int t0 = tid * 4;
  double acc[4][4];
#pragma unroll
  for (int xi = 0; xi < 4; ++xi)
#pragma unroll
    for (int k = 0; k < 4; ++k) acc[xi][k] = 0.0;

  const float4* yp = (const float4*)(y + (size_t)b * C_ * TY_) + tid;
#pragma unroll 4
  for (int c = 0; c < C_; ++c) {
    float4 yv = yp[c * (TY_ / 4)];
    double y0 = yv.x, y1 = yv.y, y2 = yv.z, y3 = yv.w;
#pragma unroll
    for (int xi = 0; xi < 4; ++xi) {
      double w = s_w[xi][c], m1 = s_m1[xi][c];
      double u0 = fma(w, y0, m1), u1 = fma(w, y1, m1);
      double u2 = fma(w, y2, m1), u3 = fma(w, y3, m1);
      acc[xi][0] = fma(u0, y0, acc[xi][0]);
      acc[xi][1] = fma(u1, y1, acc[xi][1]);
      acc[xi][2] = fma(u2, y2, acc[xi][2]);
      acc[xi][3] = fma(u3, y3, acc[xi][3]);
    }
  }

  const int xlen = xlp[b], ylen = ylp[b];
#pragma unroll
  for (int xi = 0; xi < 4; ++xi) {
    int x = x0 + xi;
    double c0 = s_t0[xi], K = s_K[xi];
    float r[4];
#pragma unroll
    for (int k = 0; k < 4; ++k)
      r[k] = (float)((acc[xi][k] + K) * (-0.5 / C_) + c0);
    *(float4*)&logp_out[((size_t)(b * TX_ + x)) * TY_ + t0] =
        make_float4(r[0], r[1], r[2], r[3]);
    bool xm = x < xlen;
#pragma unroll
    for (int k = 0; k < 4; ++k)
      tile[t0 + k][xi] = (xm && (t0 + k) < ylen) ? r[k] : NEGF;
  }
  __syncthreads();

  float* dst = lpT + (size_t)b * TY_ * TX_ + x0;
  const float4* tp = (const float4*)tile;
#pragma unroll
  for (int k = 0; k < 4; ++k) {
    int t = tid + 256 * k;
    *(float4*)&dst[(size_t)t * TX_] = tp[t];
  }
}

// ---------------------------------------------------------------------------
// Kernel B: Viterbi DP fwd + backtrack, ONE wave/batch.
// Loads land ONLY in physical banks v[128:191] (even chunks) / v[192:255]
// (odd chunks) referenced exclusively inside asm text and declared clobbers
// on every block — the allocator keeps all C++ values in v0..v127, so no
// compiler-visible value is ever a pending-load destination (R10/R11 aborts
// = late landings clobbering reallocated registers via the tied-operand
// copies).  COPYOUT does s_waitcnt THEN v_movs inside one asm block; ISSUE
// refills the just-copied bank.  Steady state: 32 loads in flight, waits
// never drain below vmcnt(16).  Tail issues nothing; vmcnt(0) before any
// post-loop register reuse.
// ---------------------------------------------------------------------------
#define ALLBANKS \
  "v128","v129","v130","v131","v132","v133","v134","v135", \
  "v136","v137","v138","v139","v140","v141","v142","v143", \
  "v144","v145","v146","v147","v148","v149","v150","v151", \
  "v152","v153","v154","v155","v156","v157","v158","v159", \
  "v160","v161","v162","v163","v164","v165","v166","v167", \
  "v168","v169","v170","v171","v172","v173","v174","v175", \
  "v176","v177","v178","v179","v180","v181","v182","v183", \
  "v184","v185","v186","v187","v188","v189","v190","v191", \
  "v192","v193","v194","v195","v196","v197","v198","v199", \
  "v200","v201","v202","v203","v204","v205","v206","v207", \
  "v208","v209","v210","v211","v212","v213","v214","v215", \
  "v216","v217","v218","v219","v220","v221","v222","v223", \
  "v224","v225","v226","v227","v228","v229","v230","v231", \
  "v232","v233","v234","v235","v236","v237","v238","v239", \
  "v240","v241","v242","v243","v244","v245","v246","v247", \
  "v248","v249","v250","v251","v252","v253","v254","v255"

#define ISSUE_BANK(R0,R1,R2,R3)                                             \
  asm volatile(                                                             \
    "global_load_dwordx4 v[" #R0 ":" #R0 "+3], %0, off\n\t"                 \
    "global_load_dwordx4 v[" #R0 "+4:" #R0 "+7], %0, off offset:1024\n\t"   \
    "global_load_dwordx4 v[" #R0 "+8:" #R0 "+11], %0, off offset:2048\n\t"  \
    "global_load_dwordx4 v[" #R0 "+12:" #R0 "+15], %0, off offset:3072\n\t" \
    "global_load_dwordx4 v[" #R1 ":" #R1 "+3], %1, off\n\t"                 \
    "global_load_dwordx4 v[" #R1 "+4:" #R1 "+7], %1, off offset:1024\n\t"   \
    "global_load_dwordx4 v[" #R1 "+8:" #R1 "+11], %1, off offset:2048\n\t"  \
    "global_load_dwordx4 v[" #R1 "+12:" #R1 "+15], %1, off offset:3072\n\t" \
    "global_load_dwordx4 v[" #R2 ":" #R2 "+3], %2, off\n\t"                 \
    "global_load_dwordx4 v[" #R2 "+4:" #R2 "+7], %2, off offset:1024\n\t"   \
    "global_load_dwordx4 v[" #R2 "+8:" #R2 "+11], %2, off offset:2048\n\t"  \
    "global_load_dwordx4 v[" #R2 "+12:" #R2 "+15], %2, off offset:3072\n\t" \
    "global_load_dwordx4 v[" #R3 ":" #R3 "+3], %3, off\n\t"                 \
    "global_load_dwordx4 v[" #R3 "+4:" #R3 "+7], %3, off offset:1024\n\t"   \
    "global_load_dwordx4 v[" #R3 "+8:" #R3 "+11], %3, off offset:2048\n\t"  \
    "global_load_dwordx4 v[" #R3 "+12:" #R3 "+15], %3, off offset:3072\n\t" \
    :: "v"(q0), "v"(q1), "v"(q2), "v"(q3) : ALLBANKS)

#define ISSUE_B0() ISSUE_BANK(128, 144, 160, 176)
#define ISSUE_B1() ISSUE_BANK(192, 208, 224, 240)

// one 16-float copy block; WAITSTR = "s_waitcnt vmcnt(N)\n\t" or ""
#define CP16(WAITSTR, R, c, o)                                              \
  asm volatile(WAITSTR                                                      \
    "v_mov_b32 %0, v[" #R "]\n\t"   "v_mov_b32 %1, v[" #R "+1]\n\t"         \
    "v_mov_b32 %2, v[" #R "+2]\n\t" "v_mov_b32 %3, v[" #R "+3]\n\t"         \
    "v_mov_b32 %4, v[" #R "+4]\n\t" "v_mov_b32 %5, v[" #R "+5]\n\t"         \
    "v_mov_b32 %6, v[" #R "+6]\n\t" "v_mov_b32 %7, v[" #R "+7]\n\t"         \
    "v_mov_b32 %8, v[" #R "+8]\n\t" "v_mov_b32 %9, v[" #R "+9]\n\t"         \
    "v_mov_b32 %10, v[" #R "+10]\n\t" "v_mov_b32 %11, v[" #R "+11]\n\t"     \
    "v_mov_b32 %12, v[" #R "+12]\n\t" "v_mov_b32 %13, v[" #R "+13]\n\t"     \
    "v_mov_b32 %14, v[" #R "+14]\n\t" "v_mov_b32 %15, v[" #R "+15]"         \
    : "=v"((c)[(o)+0]), "=v"((c)[(o)+1]), "=v"((c)[(o)+2]), "=v"((c)[(o)+3]),\
      "=v"((c)[(o)+4]), "=v"((c)[(o)+5]), "=v"((c)[(o)+6]), "=v"((c)[(o)+7]),\
      "=v"((c)[(o)+8]), "=v"((c)[(o)+9]), "=v"((c)[(o)+10]),"=v"((c)[(o)+11]),\
      "=v"((c)[(o)+12]),"=v"((c)[(o)+13]),"=v"((c)[(o)+14]),"=v"((c)[(o)+15])\
    :: ALLBANKS)

#define COPYOUT_B0(WAITSTR, c)                                              \
  CP16(WAITSTR, 128, c, 0);  CP16("", 144, c, 16);                          \
  CP16("", 160, c, 32);      CP16("", 176, c, 48)
#define COPYOUT_B1(WAITSTR, c)                                              \
  CP16(WAITSTR, 192, c, 0);  CP16("", 208, c, 16);                          \
  CP16("", 224, c, 32);      CP16("", 240, c, 48)

#define ADV() { q0 += 4096; q1 += 4096; q2 += 4096; q3 += 4096; }

#define CONSUME16C(c, k)                                                    \
  {                                                                         \
    const int sb = ((k) & 1) << 4;                                          \
    _Pragma("unroll")                                                       \
    for (int i = 0; i < 16; ++i) {                                          \
      const float vs0 = sh;                                                 \
      const uint32_t bit = 1u << (sb + i);                                  \
      if (vs0 > v0) b0 |= bit;                                              \
      if (v0 > v1)  b1 |= bit;                                              \
      if (v1 > v2)  b2 |= bit;                                              \
      if (v2 > v3)  b3 |= bit;                                              \
      float nv3 = (c)[4*i+3] + fmaxf(v3, v2);                               \
      sh = dpp_shr1_negfill_f32(nv3);                                       \
      float nv2 = (c)[4*i+2] + fmaxf(v2, v1);                               \
      float nv1 = (c)[4*i+1] + fmaxf(v1, v0);                               \
      float nv0 = (c)[4*i+0] + fmaxf(v0, vs0);                              \
      v0 = nv0; v1 = nv1; v2 = nv2; v3 = nv3;                               \
    }                                                                       \
    if ((k) & 1) {                                                          \
      const int w = (k) >> 1;                                               \
      uint4 pk; pk.x = b0; pk.y = b1; pk.z = b2; pk.w = b3;                 \
      *(uint4*)&bits[w * 256 + 4 * lane] = pk;                              \
      b0 = b1 = b2 = b3 = 0;                                                \
    }                                                                       \
  }

__global__ __launch_bounds__(64, 1) void k_dp(
    const float* __restrict__ lpT, const int* __restrict__ xlp,
    const int* __restrict__ ylp, float* __restrict__ dr_out,
    int* __restrict__ cum_ws, int* __restrict__ xt_ws)
{
  const int b = blockIdx.x;
  const int lane = threadIdx.x;
  __shared__ uint32_t bits[8192];            // [w*256 + x], 32 KB
  __shared__ uint32_t dur[TX_];

  // 4 persistent base pointers (cols 0-3 / 4-7 / 8-11 / 12-15 of the chunk)
  const float* q0 = lpT + (size_t)b * TY_ * TX_ + 4 * lane;
  const float* q1 = q0 + 1024;
  const float* q2 = q0 + 2048;
  const float* q3 = q0 + 3072;

  float v0 = (lane == 0) ? 0.0f : NEGF, v1 = NEGF, v2 = NEGF, v3 = NEGF;
  float sh = NEGF;
  uint32_t b0 = 0, b1 = 0, b2 = 0, b3 = 0;
  float c[64];

  // prologue: chunk0 -> bank0, chunk1 -> bank1 (32 loads in flight)
  ISSUE_B0(); ADV();
  ISSUE_B1(); ADV();

  for (int p = 0; p < 62; p += 2) {
    // even phase p: chunk p in bank0
    COPYOUT_B0("s_waitcnt vmcnt(16)\n\t", c);  // chunk p landed; p+1 in flight
    ISSUE_B0(); ADV();                          // chunk p+2 -> bank0
    CONSUME16C(c, p);
    // odd phase p+1: chunk p+1 in bank1
    COPYOUT_B1("s_waitcnt vmcnt(16)\n\t", c);  // chunk p+1 landed; p+2 in flight
    ISSUE_B1(); ADV();                          // chunk p+3 -> bank1
    CONSUME16C(c, p + 1);
  }
  // phase 62: chunks 62,63 outstanding; no more issues
  COPYOUT_B0("s_waitcnt vmcnt(16)\n\t", c);
  CONSUME16C(c, 62);
  // phase 63: drain fully
  COPYOUT_B1("s_waitcnt vmcnt(0)\n\t", c);
  CONSUME16C(c, 63);
  asm volatile("s_waitcnt vmcnt(0)" ::: "memory");  // belt and suspenders

#pragma unroll
  for (int j = 0; j < 4; ++j) dur[4 * lane + j] = 0;
  __syncthreads();

  const int xlen = xlp[b], ylen = ylp[b];
  if (lane == 0) {
    int idx = xlen - 1;
    int t = ylen - 1;
    while (t >= 0) {
      if (idx == 0) { dur[0] += (uint32_t)(t + 1); break; }
      int w = t >> 5, rr = t & 31;
      uint32_t word = bits[w * 256 + idx];
      word &= (rr == 31) ? 0xffffffffu : ((1u << (rr + 1)) - 1u);
      while (word == 0 && w > 0) { --w; word = bits[w * 256 + idx]; }
      if (word == 0) { dur[idx] += (uint32_t)(t + 1); break; }
      int bitpos = 31 - __builtin_clz(word);
      int tp = (w << 5) | bitpos;        // step where diag fires -> decrement
      dur[idx] += (uint32_t)(t - tp + 1);
      --idx;
      t = tp - 1;
    }
  }
  __syncthreads();

  // wave-wide inclusive scan of durations -> cum, dr, and t->x scatter map
  uint32_t d0 = dur[4 * lane], d1 = dur[4 * lane + 1];
  uint32_t d2 = dur[4 * lane + 2], d3 = dur[4 * lane + 3];
  uint32_t own = d0 + d1 + d2 + d3;
  uint32_t s = own;
#pragma unroll
  for (int off = 1; off < 64; off <<= 1) {
    uint32_t n = __shfl_up(s, off);
    if (lane >= off) s += n;
  }
  uint32_t base = s - own;
  uint32_t c0 = base + d0, c1 = c0 + d1, c2 = c1 + d2, c3 = c2 + d3;
  int x = 4 * lane;
  cum_ws[b * TX_ + x]     = (int)c0;
  cum_ws[b * TX_ + x + 1] = (int)c1;
  cum_ws[b * TX_ + x + 2] = (int)c2;
  cum_ws[b * TX_ + x + 3] = (int)c3;
  dr_out[b * TX_ + x]     = (float)d0;
  dr_out[b * TX_ + x + 1] = (float)d1;
  dr_out[b * TX_ + x + 2] = (float)d2;
  dr_out[b * TX_ + x + 3] = (float)d3;
  int* xt = xt_ws + b * TY_;
  for (uint32_t t = c0 - d0; t < c0; ++t) xt[t] = x;
  for (uint32_t t = c1 - d1; t < c1; ++t) xt[t] = x + 1;
  for (uint32_t t = c2 - d2; t < c2; ++t) xt[t] = x + 2;
  for (uint32_t t = c3 - d3; t < c3; ++t) xt[t] = x + 3;
}

// ---------------------------------------------------------------------------
// Kernel C (fused epilogue): blocks [0,TX) write attn rows from cum;
// blocks [TX,TX+H) gather o_en_ex[b,h,t] = t<ylen ? en[b,h,xt[b,t]] : 0.
// ---------------------------------------------------------------------------
__global__ __launch_bounds__(256) void k_epi(
    const int* __restrict__ cum_ws, const int* __restrict__ xt_ws,
    const float* __restrict__ en, const int* __restrict__ ylp,
    float* __restrict__ attn, float* __restrict__ oen)
{
  const int b = blockIdx.y, bx = blockIdx.x, tid = threadIdx.x;
  __shared__ float row[TX_];
  if (bx < TX_) {
    const int x = bx;
    int hi = cum_ws[b * TX_ + x];
    int lo = (x > 0) ? cum_ws[b * TX_ + x - 1] : 0;
    int t0 = tid * 4;
    float4 v;
    v.x = (t0     >= lo && t0     < hi) ? 1.f : 0.f;
    v.y = (t0 + 1 >= lo && t0 + 1 < hi) ? 1.f : 0.f;
    v.z = (t0 + 2 >= lo && t0 + 2 < hi) ? 1.f : 0.f;
    v.w = (t0 + 3 >= lo && t0 + 3 < hi) ? 1.f : 0.f;
    *(float4*)&attn[((size_t)(b * TX_ + x)) * TY_ + t0] = v;
  } else {
    const int h = bx - TX_;
    row[tid] = en[((size_t)(b * H_ + h)) * TX_ + tid];
    __syncthreads();
    const int ylen = ylp[b];
    int t0 = tid * 4;
    int4 xi = *(const int4*)&xt_ws[b * TY_ + t0];
    float4 v;
    v.x = (t0     < ylen) ? row[xi.x & (TX_ - 1)] : 0.f;
    v.y = (t0 + 1 < ylen) ? row[xi.y & (TX_ - 1)] : 0.f;
    v.z = (t0 + 2 < ylen) ? row[xi.z & (TX_ - 1)] : 0.f;
    v.w = (t0 + 3 < ylen) ? row[xi.w & (TX_ - 1)] : 0.f;
    *(float4*)&oen[((size_t)(b * H_ + h)) * TY_ + t0] = v;
  }
}

extern "C" void kernel_launch(void* const* d_in, const int* in_sizes, int n_in,
                              void* d_out, int out_size, void* d_ws, size_t ws_size,
                              hipStream_t stream)
{
  const float* en = (const float*)d_in[0];
  const float* mu = (const float*)d_in[1];
  const float* ls = (const float*)d_in[2];
  const float* y  = (const float*)d_in[3];
  const int*   xl = (const int*)d_in[4];
  const int*   yl = (const int*)d_in[5];

  float* out  = (float*)d_out;
  float* oen  = out;             // [B,H,TY]
  float* logp = out + OFF_LOGP;  // [B,TX,TY]
  float* attn = out + OFF_ATTN;  // [B,TX,TY] (doubles as lpT scratch first)
  float* dr   = out + OFF_DR;    // [B,TX]

  int* cum = (int*)d_ws;               // B*TX ints
  int* xt  = cum + B_ * TX_;           // B*TY ints

  k_logp<<<dim3(TX_ / 4, B_),   256, 0, stream>>>(mu, ls, y, xl, yl, logp, attn);
  k_dp  <<<B_,                   64, 0, stream>>>(attn, xl, yl, dr, cum, xt);
  k_epi <<<dim3(TX_ + H_, B_),  256, 0, stream>>>(cum, xt, en, yl, attn, oen);
}

// Round 13
// 188.129 us; speedup vs baseline: 2.6133x; 1.0534x over previous
//
#include <hip/hip_runtime.h>
#include <cstdint>
#include <cmath>

#define B_ 4
#define H_ 256
#define C_ 80
#define TX_ 256
#define TY_ 1024
#define NC_ 64                 // chunks of 16 columns
#define NEGF (-1e9f)

// output layout (floats): o_en_ex [B,H,TY] | logp [B,TX,TY] | attn [B,TX,TY] | dr [B,TX]
#define OFF_LOGP (B_*H_*TY_)
#define OFF_ATTN (OFF_LOGP + B_*TX_*TY_)
#define OFF_DR   (OFF_ATTN + B_*TX_*TY_)

// __shfl_up(x,1) as pure VALU: DPP wave_shr:1 (ctrl 0x138); lane 0 gets NEGF.
__device__ __forceinline__ float dpp_shr1_negfill_f32(float x) {
  union { float f; int i; } u, o, r;
  u.f = x; o.f = NEGF;
  r.i = __builtin_amdgcn_update_dpp(o.i, u.i, 0x138, 0xf, 0xf, false);
  return r.f;
}

// ---------------------------------------------------------------------------
// Kernel A: logp (unchanged, passing since R5).
// ---------------------------------------------------------------------------
__global__ __launch_bounds__(256) void k_logp(
    const float* __restrict__ mu, const float* __restrict__ ls,
    const float* __restrict__ y, const int* __restrict__ xlp,
    const int* __restrict__ ylp, float* __restrict__ logp_out,
    float* __restrict__ lpT)
{
  const int b  = blockIdx.y;
  const int x0 = blockIdx.x * 4;
  const int tid = threadIdx.x;
  __shared__ double s_w[4][C_];
  __shared__ double s_m1[4][C_];
  __shared__ double s_wm2[4][C_];
  __shared__ double s_lsv[4][C_];
  __shared__ double s_K[4];
  __shared__ double s_t0[4];
  __shared__ float tile[TY_][4];
  for (int i = tid; i < 4 * C_; i += 256) {
    int xi = i / C_, c = i - xi * C_;
    double m = (double)mu[(b * C_ + c) * TX_ + x0 + xi];
    double l = (double)ls[(b * C_ + c) * TX_ + x0 + xi];
    double w = exp(-2.0 * l);
    s_w[xi][c]   = w;
    s_m1[xi][c]  = -2.0 * w * m;
    s_wm2[xi][c] = w * m * m;
    s_lsv[xi][c] = l;
  }
  __syncthreads();
  {
    int xi = tid >> 6, cc = tid & 63;
    double kp = (cc < C_) ? s_wm2[xi][cc] : 0.0;
    double tp = (cc < C_) ? s_lsv[xi][cc] : 0.0;
    if (cc + 64 < C_) { kp += s_wm2[xi][cc + 64]; tp += s_lsv[xi][cc + 64]; }
#pragma unroll
    for (int off = 32; off; off >>= 1) {
      kp += __shfl_down(kp, off);
      tp += __shfl_down(tp, off);
    }
    if (cc == 0) { s_K[xi] = kp; s_t0[xi] = -0.5 * (tp * (1.0 / C_)); }
  }
  __syncthreads();

  const int t0 = tid * 4;
  double acc[4][4];
#pragma unroll
  for (int xi = 0; xi < 4; ++xi)
#pragma unroll
    for (int k = 0; k < 4; ++k) acc[xi][k] = 0.0;

  const float4* yp = (const float4*)(y + (size_t)b * C_ * TY_) + tid;
#pragma unroll 4
  for (int c = 0; c < C_; ++c) {
    float4 yv = yp[c * (TY_ / 4)];
    double y0 = yv.x, y1 = yv.y, y2 = yv.z, y3 = yv.w;
#pragma unroll
    for (int xi = 0; xi < 4; ++xi) {
      double w = s_w[xi][c], m1 = s_m1[xi][c];
      double u0 = fma(w, y0, m1), u1 = fma(w, y1, m1);
      double u2 = fma(w, y2, m1), u3 = fma(w, y3, m1);
      acc[xi][0] = fma(u0, y0, acc[xi][0]);
      acc[xi][1] = fma(u1, y1, acc[xi][1]);
      acc[xi][2] = fma(u2, y2, acc[xi][2]);
      acc[xi][3] = fma(u3, y3, acc[xi][3]);
    }
  }

  const int xlen = xlp[b], ylen = ylp[b];
#pragma unroll
  for (int xi = 0; xi < 4; ++xi) {
    int x = x0 + xi;
    double c0 = s_t0[xi], K = s_K[xi];
    float r[4];
#pragma unroll
    for (int k = 0; k < 4; ++k)
      r[k] = (float)((acc[xi][k] + K) * (-0.5 / C_) + c0);
    *(float4*)&logp_out[((size_t)(b * TX_ + x)) * TY_ + t0] =
        make_float4(r[0], r[1], r[2], r[3]);
    bool xm = x < xlen;
#pragma unroll
    for (int k = 0; k < 4; ++k)
      tile[t0 + k][xi] = (xm && (t0 + k) < ylen) ? r[k] : NEGF;
  }
  __syncthreads();

  float* dst = lpT + (size_t)b * TY_ * TX_ + x0;
  const float4* tp = (const float4*)tile;
#pragma unroll
  for (int k = 0; k < 4; ++k) {
    int t = tid + 256 * k;
    *(float4*)&dst[(size_t)t * TX_] = tp[t];
  }
}

// ---------------------------------------------------------------------------
// Kernel B: Viterbi DP, 4 SKEWED WAVES per batch (256 thr, thread = one x).
// R6-R12 all plateaued at ~190 cyc/column with ONE wave/batch — the single-
// wave organization is the structural floor (T >= L/2, 1KB/col).  Here the
// recurrence v[x] = col + max(v[x], v[x-1]) is split across 4 waves: within-
// wave neighbor via DPP, cross-wave via an LDS boundary series; wave w runs
// chunk c at phase w+c (skew), so only a 16-float series crosses waves per
// phase.  Per phase each wave prefetches its 16-dword slice of chunk c+2
// (tiny reg buffers -> no allocator fight), consumes chunk c from regs.
// Phase barrier = raw `s_waitcnt lgkmcnt(0); s_barrier` (drains LDS for the
// boundary/bits handoff but NOT vmcnt -> prefetches stay in flight; compiler
// emits precise vmcnt for the consume).  Math bit-identical to R12.
// Backtrack: dur[] writes are first-visit -> plain stores (no LDS RMW).
// LDS: bits 32KB + dur 1KB + bdry/dummy ~1KB.
// ---------------------------------------------------------------------------
#define PHASE_BAR() \
  asm volatile("s_waitcnt lgkmcnt(0)\n\ts_barrier" ::: "memory")

#define PHASEQ(FL, FC, q)                                                   \
  {                                                                         \
    const int cl = (q) - w;                                                 \
    if (cl >= 0 && cl < NC_) {                                              \
      const float* cb = gb + (size_t)cl * 16 * TX_ + tid;                   \
      _Pragma("unroll")                                                     \
      for (int i = 0; i < 16; ++i) FL[i] = cb[i * TX_];                     \
    }                                                                       \
    const int cc = (q) - 2 - w;                                             \
    if (cc >= 0 && cc < NC_) {                                              \
      if (cc == 0) { v = (tid == 0) ? 0.0f : NEGF; word = 0u; }             \
      const uint32_t bitbase = 1u << ((cc & 1) << 4);                       \
      float* wr = (lane == 63) ? &bdry[cc & 1][w + 1][0] : &dummy[lane];    \
      const float* bp = &bdry[cc & 1][w][0];                                \
      float bv[16];                                                         \
      *(float4*)&bv[0]  = *(const float4*)(bp);                             \
      *(float4*)&bv[4]  = *(const float4*)(bp + 4);                         \
      *(float4*)&bv[8]  = *(const float4*)(bp + 8);                         \
      *(float4*)&bv[12] = *(const float4*)(bp + 12);                        \
      wr[0] = v;                                                            \
      _Pragma("unroll")                                                     \
      for (int i = 0; i < 16; ++i) {                                        \
        float vl = dpp_shr1_negfill_f32(v);                                 \
        if (amlane0) vl = bv[i];                                            \
        if (vl > v) word |= (bitbase << i);                                 \
        float nv = FC[i] + fmaxf(v, vl);                                    \
        if (i < 15) wr[i + 1] = nv;                                         \
        v = nv;                                                             \
      }                                                                     \
      if (cc & 1) { bits[(cc >> 1) * 256 + tid] = word; word = 0u; }        \
    }                                                                       \
    PHASE_BAR();                                                            \
  }

__global__ __launch_bounds__(256, 1) void k_dp(
    const float* __restrict__ lpT, const int* __restrict__ xlp,
    const int* __restrict__ ylp, float* __restrict__ dr_out,
    int* __restrict__ cum_ws, int* __restrict__ xt_ws)
{
  const int b = blockIdx.x;
  const int tid = threadIdx.x;            // = x
  const int lane = tid & 63;
  const int w = tid >> 6;                 // wave id 0..3
  __shared__ uint32_t bits[8192];         // [wword*256 + x], 32 KB
  __shared__ uint32_t dur[TX_];
  __shared__ float bdry[2][5][16];        // [chunk parity][dest wave][col]
  __shared__ float dummy[80];             // absorbs non-lane63 bdry writes

  const float* gb = lpT + (size_t)b * TY_ * TX_;
  const bool amlane0 = (w > 0) && (lane == 0);

  float v = NEGF;                         // set properly at cc==0
  uint32_t word = 0;
  float f0[16], f1[16], f2[16];

  // phases q=0..68: wave w loads chunk q-w, consumes chunk q-2-w.
  for (int q = 0; q < 69; q += 3) {
    PHASEQ(f0, f1, q);
    PHASEQ(f1, f2, q + 1);
    PHASEQ(f2, f0, q + 2);
  }
  __syncthreads();

  dur[tid] = 0;
  __syncthreads();

  const int xlen = xlp[b], ylen = ylp[b];
  if (tid == 0) {
    int idx = xlen - 1;
    int t = ylen - 1;
    while (t >= 0) {
      if (idx == 0) { dur[0] = (uint32_t)(t + 1); break; }
      int ww = t >> 5, rr = t & 31;
      uint32_t wd = bits[ww * 256 + idx];
      wd &= (rr == 31) ? 0xffffffffu : ((1u << (rr + 1)) - 1u);
      while (wd == 0 && ww > 0) { --ww; wd = bits[ww * 256 + idx]; }
      if (wd == 0) { dur[idx] = (uint32_t)(t + 1); break; }
      int bitpos = 31 - __builtin_clz(wd);
      int tp = (ww << 5) | bitpos;       // step where diag fires -> decrement
      dur[idx] = (uint32_t)(t - tp + 1); // first visit of idx -> plain store
      --idx;
      t = tp - 1;
    }
  }
  __syncthreads();

  if (w == 0) {
    // wave-wide inclusive scan of durations -> cum, dr, and t->x scatter map
    uint32_t d0 = dur[4 * lane], d1 = dur[4 * lane + 1];
    uint32_t d2 = dur[4 * lane + 2], d3 = dur[4 * lane + 3];
    uint32_t own = d0 + d1 + d2 + d3;
    uint32_t s = own;
#pragma unroll
    for (int off = 1; off < 64; off <<= 1) {
      uint32_t n = __shfl_up(s, off);
      if (lane >= off) s += n;
    }
    uint32_t base = s - own;
    uint32_t c0 = base + d0, c1 = c0 + d1, c2 = c1 + d2, c3 = c2 + d3;
    int x = 4 * lane;
    cum_ws[b * TX_ + x]     = (int)c0;
    cum_ws[b * TX_ + x + 1] = (int)c1;
    cum_ws[b * TX_ + x + 2] = (int)c2;
    cum_ws[b * TX_ + x + 3] = (int)c3;
    dr_out[b * TX_ + x]     = (float)d0;
    dr_out[b * TX_ + x + 1] = (float)d1;
    dr_out[b * TX_ + x + 2] = (float)d2;
    dr_out[b * TX_ + x + 3] = (float)d3;
    int* xt = xt_ws + b * TY_;
    for (uint32_t t = c0 - d0; t < c0; ++t) xt[t] = x;
    for (uint32_t t = c1 - d1; t < c1; ++t) xt[t] = x + 1;
    for (uint32_t t = c2 - d2; t < c2; ++t) xt[t] = x + 2;
    for (uint32_t t = c3 - d3; t < c3; ++t) xt[t] = x + 3;
  }
}

// ---------------------------------------------------------------------------
// Kernel C (fused epilogue): blocks [0,TX) write attn rows from cum;
// blocks [TX,TX+H) gather o_en_ex[b,h,t] = t<ylen ? en[b,h,xt[b,t]] : 0.
// ---------------------------------------------------------------------------
__global__ __launch_bounds__(256) void k_epi(
    const int* __restrict__ cum_ws, const int* __restrict__ xt_ws,
    const float* __restrict__ en, const int* __restrict__ ylp,
    float* __restrict__ attn, float* __restrict__ oen)
{
  const int b = blockIdx.y, bx = blockIdx.x, tid = threadIdx.x;
  __shared__ float row[TX_];
  if (bx < TX_) {
    const int x = bx;
    int hi = cum_ws[b * TX_ + x];
    int lo = (x > 0) ? cum_ws[b * TX_ + x - 1] : 0;
    int t0 = tid * 4;
    float4 v;
    v.x = (t0     >= lo && t0     < hi) ? 1.f : 0.f;
    v.y = (t0 + 1 >= lo && t0 + 1 < hi) ? 1.f : 0.f;
    v.z = (t0 + 2 >= lo && t0 + 2 < hi) ? 1.f : 0.f;
    v.w = (t0 + 3 >= lo && t0 + 3 < hi) ? 1.f : 0.f;
    *(float4*)&attn[((size_t)(b * TX_ + x)) * TY_ + t0] = v;
  } else {
    const int h = bx - TX_;
    row[tid] = en[((size_t)(b * H_ + h)) * TX_ + tid];
    __syncthreads();
    const int ylen = ylp[b];
    int t0 = tid * 4;
    int4 xi = *(const int4*)&xt_ws[b * TY_ + t0];
    float4 v;
    v.x = (t0     < ylen) ? row[xi.x & (TX_ - 1)] : 0.f;
    v.y = (t0 + 1 < ylen) ? row[xi.y & (TX_ - 1)] : 0.f;
    v.z = (t0 + 2 < ylen) ? row[xi.z & (TX_ - 1)] : 0.f;
    v.w = (t0 + 3 < ylen) ? row[xi.w & (TX_ - 1)] : 0.f;
    *(float4*)&oen[((size_t)(b * H_ + h)) * TY_ + t0] = v;
  }
}

extern "C" void kernel_launch(void* const* d_in, const int* in_sizes, int n_in,
                              void* d_out, int out_size, void* d_ws, size_t ws_size,
                              hipStream_t stream)
{
  const float* en = (const float*)d_in[0];
  const float* mu = (const float*)d_in[1];
  const float* ls = (const float*)d_in[2];
  const float* y  = (const float*)d_in[3];
  const int*   xl = (const int*)d_in[4];
  const int*   yl = (const int*)d_in[5];

  float* out  = (float*)d_out;
  float* oen  = out;             // [B,H,TY]
  float* logp = out + OFF_LOGP;  // [B,TX,TY]
  float* attn = out + OFF_ATTN;  // [B,TX,TY] (doubles as lpT scratch first)
  float* dr   = out + OFF_DR;    // [B,TX]

  int* cum = (int*)d_ws;               // B*TX ints
  int* xt  = cum + B_ * TX_;           // B*TY ints

  k_logp<<<dim3(TX_ / 4, B_),   256, 0, stream>>>(mu, ls, y, xl, yl, logp, attn);
  k_dp  <<<B_,                  256, 0, stream>>>(attn, xl, yl, dr, cum, xt);
  k_epi <<<dim3(TX_ + H_, B_),  256, 0, stream>>>(cum, xt, en, yl, attn, oen);
}

// Round 14
// 184.277 us; speedup vs baseline: 2.6679x; 1.0209x over previous
//
#include <hip/hip_runtime.h>
#include <cstdint>
#include <cmath>

#define B_ 4
#define H_ 256
#define C_ 80
#define TX_ 256
#define TY_ 1024
#define NC_ 64                 // chunks of 16 columns
#define NEGF (-1e9f)

// output layout (floats): o_en_ex [B,H,TY] | logp [B,TX,TY] | attn [B,TX,TY] | dr [B,TX]
#define OFF_LOGP (B_*H_*TY_)
#define OFF_ATTN (OFF_LOGP + B_*TX_*TY_)
#define OFF_DR   (OFF_ATTN + B_*TX_*TY_)

// __shfl_up(x,1) as pure VALU: DPP wave_shr:1 (ctrl 0x138); lane 0 gets NEGF.
__device__ __forceinline__ float dpp_shr1_negfill_f32(float x) {
  union { float f; int i; } u, o, r;
  u.f = x; o.f = NEGF;
  r.i = __builtin_amdgcn_update_dpp(o.i, u.i, 0x138, 0xf, 0xf, false);
  return r.f;
}

// ---------------------------------------------------------------------------
// Kernel A: logp (unchanged, passing since R5).
// ---------------------------------------------------------------------------
__global__ __launch_bounds__(256) void k_logp(
    const float* __restrict__ mu, const float* __restrict__ ls,
    const float* __restrict__ y, const int* __restrict__ xlp,
    const int* __restrict__ ylp, float* __restrict__ logp_out,
    float* __restrict__ lpT)
{
  const int b  = blockIdx.y;
  const int x0 = blockIdx.x * 4;
  const int tid = threadIdx.x;
  __shared__ double s_w[4][C_];
  __shared__ double s_m1[4][C_];
  __shared__ double s_wm2[4][C_];
  __shared__ double s_lsv[4][C_];
  __shared__ double s_K[4];
  __shared__ double s_t0[4];
  __shared__ float tile[TY_][4];
  for (int i = tid; i < 4 * C_; i += 256) {
    int xi = i / C_, c = i - xi * C_;
    double m = (double)mu[(b * C_ + c) * TX_ + x0 + xi];
    double l = (double)ls[(b * C_ + c) * TX_ + x0 + xi];
    double w = exp(-2.0 * l);
    s_w[xi][c]   = w;
    s_m1[xi][c]  = -2.0 * w * m;
    s_wm2[xi][c] = w * m * m;
    s_lsv[xi][c] = l;
  }
  __syncthreads();
  {
    int xi = tid >> 6, cc = tid & 63;
    double kp = (cc < C_) ? s_wm2[xi][cc] : 0.0;
    double tp = (cc < C_) ? s_lsv[xi][cc] : 0.0;
    if (cc + 64 < C_) { kp += s_wm2[xi][cc + 64]; tp += s_lsv[xi][cc + 64]; }
#pragma unroll
    for (int off = 32; off; off >>= 1) {
      kp += __shfl_down(kp, off);
      tp += __shfl_down(tp, off);
    }
    if (cc == 0) { s_K[xi] = kp; s_t0[xi] = -0.5 * (tp * (1.0 / C_)); }
  }
  __syncthreads();

  const int t0 = tid * 4;
  double acc[4][4];
#pragma unroll
  for (int xi = 0; xi < 4; ++xi)
#pragma unroll
    for (int k = 0; k < 4; ++k) acc[xi][k] = 0.0;

  const float4* yp = (const float4*)(y + (size_t)b * C_ * TY_) + tid;
#pragma unroll 4
  for (int c = 0; c < C_; ++c) {
    float4 yv = yp[c * (TY_ / 4)];
    double y0 = yv.x, y1 = yv.y, y2 = yv.z, y3 = yv.w;
#pragma unroll
    for (int xi = 0; xi < 4; ++xi) {
      double w = s_w[xi][c], m1 = s_m1[xi][c];
      double u0 = fma(w, y0, m1), u1 = fma(w, y1, m1);
      double u2 = fma(w, y2, m1), u3 = fma(w, y3, m1);
      acc[xi][0] = fma(u0, y0, acc[xi][0]);
      acc[xi][1] = fma(u1, y1, acc[xi][1]);
      acc[xi][2] = fma(u2, y2, acc[xi][2]);
      acc[xi][3] = fma(u3, y3, acc[xi][3]);
    }
  }

  const int xlen = xlp[b], ylen = ylp[b];
#pragma unroll
  for (int xi = 0; xi < 4; ++xi) {
    int x = x0 + xi;
    double c0 = s_t0[xi], K = s_K[xi];
    float r[4];
#pragma unroll
    for (int k = 0; k < 4; ++k)
      r[k] = (float)((acc[xi][k] + K) * (-0.5 / C_) + c0);
    *(float4*)&logp_out[((size_t)(b * TX_ + x)) * TY_ + t0] =
        make_float4(r[0], r[1], r[2], r[3]);
    bool xm = x < xlen;
#pragma unroll
    for (int k = 0; k < 4; ++k)
      tile[t0 + k][xi] = (xm && (t0 + k) < ylen) ? r[k] : NEGF;
  }
  __syncthreads();

  float* dst = lpT + (size_t)b * TY_ * TX_ + x0;
  const float4* tp = (const float4*)tile;
#pragma unroll
  for (int k = 0; k < 4; ++k) {
    int t = tid + 256 * k;
    *(float4*)&dst[(size_t)t * TX_] = tp[t];
  }
}

// ---------------------------------------------------------------------------
// Kernel B: Viterbi DP, 4 skewed waves per batch (thread = one x).
// R13 post-mortem: the prefetch loads were inside `if (cl in range)` — a
// branch — so the compiler could not statically count outstanding loads and
// emitted vmcnt(0)每phase (full pipeline drain -> 2400 cyc/phase).  Fix:
// UNCONDITIONAL loads with a clamped chunk index (static counts -> precise
// vmcnt(48)), and 4 rotating buffers for a 3-phase prefetch distance.
// Cross-wave recurrence handoff via LDS boundary series (1-phase skew);
// phase barrier = raw `s_waitcnt lgkmcnt(0); s_barrier` (drains LDS only —
// global prefetches stay in flight).  Math bit-identical to R12/R13.
// LDS: bits 32KB + dur 1KB + bdry/dummy ~1KB.
// ---------------------------------------------------------------------------
#define PHASE_BAR() \
  asm volatile("s_waitcnt lgkmcnt(0)\n\ts_barrier" ::: "memory")

#define PHASEQ(FL, FC, q)                                                   \
  {                                                                         \
    const int cl = (q) - w;                                                 \
    const int clc = cl < 0 ? 0 : (cl >= NC_ ? NC_ - 1 : cl);                \
    const float* cb = gb + (size_t)clc * 16 * TX_ + tid;                    \
    _Pragma("unroll")                                                       \
    for (int i = 0; i < 16; ++i) FL[i] = cb[i * TX_];   /* UNCONDITIONAL */ \
    const int cc = (q) - 3 - w;                                             \
    if (cc >= 0 && cc < NC_) {                                              \
      if (cc == 0) { v = (tid == 0) ? 0.0f : NEGF; word = 0u; }             \
      const uint32_t bitbase = 1u << ((cc & 1) << 4);                       \
      float* wr = (lane == 63) ? &bdry[cc & 1][w + 1][0] : &dummy[lane];    \
      const float* bp = &bdry[cc & 1][w][0];                                \
      float bv[16];                                                         \
      *(float4*)&bv[0]  = *(const float4*)(bp);                             \
      *(float4*)&bv[4]  = *(const float4*)(bp + 4);                         \
      *(float4*)&bv[8]  = *(const float4*)(bp + 8);                         \
      *(float4*)&bv[12] = *(const float4*)(bp + 12);                        \
      wr[0] = v;                                                            \
      _Pragma("unroll")                                                     \
      for (int i = 0; i < 16; ++i) {                                        \
        float vl = dpp_shr1_negfill_f32(v);                                 \
        if (amlane0) vl = bv[i];                                            \
        if (vl > v) word |= (bitbase << i);                                 \
        float nv = FC[i] + fmaxf(v, vl);                                    \
        if (i < 15) wr[i + 1] = nv;                                         \
        v = nv;                                                             \
      }                                                                     \
      if (cc & 1) { bits[(cc >> 1) * 256 + tid] = word; word = 0u; }        \
    }                                                                       \
    PHASE_BAR();                                                            \
  }

__global__ __launch_bounds__(256, 1) void k_dp(
    const float* __restrict__ lpT, const int* __restrict__ xlp,
    const int* __restrict__ ylp, float* __restrict__ dr_out,
    int* __restrict__ cum_ws, int* __restrict__ xt_ws)
{
  const int b = blockIdx.x;
  const int tid = threadIdx.x;            // = x
  const int lane = tid & 63;
  const int w = tid >> 6;                 // wave id 0..3
  __shared__ uint32_t bits[8192];         // [wword*256 + x], 32 KB
  __shared__ uint32_t dur[TX_];
  __shared__ float bdry[2][5][16];        // [chunk parity][dest wave][col]
  __shared__ float dummy[80];             // absorbs non-lane63 bdry writes

  const float* gb = lpT + (size_t)b * TY_ * TX_;
  const bool amlane0 = (w > 0) && (lane == 0);

  float v = NEGF;                         // set properly at cc==0
  uint32_t word = 0;
  float f0[16], f1[16], f2[16], f3[16];

  // phases q=0..71: wave w loads chunk clamp(q-w), consumes chunk q-3-w.
  // buffer loaded at phase p is consumed at phase p+3 (4-slot rotation).
  for (int q = 0; q < 72; q += 4) {
    PHASEQ(f0, f1, q);
    PHASEQ(f1, f2, q + 1);
    PHASEQ(f2, f3, q + 2);
    PHASEQ(f3, f0, q + 3);
  }
  __syncthreads();

  dur[tid] = 0;
  __syncthreads();

  const int xlen = xlp[b], ylen = ylp[b];
  if (tid == 0) {
    int idx = xlen - 1;
    int t = ylen - 1;
    while (t >= 0) {
      if (idx == 0) { dur[0] = (uint32_t)(t + 1); break; }
      int ww = t >> 5, rr = t & 31;
      uint32_t wd = bits[ww * 256 + idx];
      wd &= (rr == 31) ? 0xffffffffu : ((1u << (rr + 1)) - 1u);
      while (wd == 0 && ww > 0) { --ww; wd = bits[ww * 256 + idx]; }
      if (wd == 0) { dur[idx] = (uint32_t)(t + 1); break; }
      int bitpos = 31 - __builtin_clz(wd);
      int tp = (ww << 5) | bitpos;       // step where diag fires -> decrement
      dur[idx] = (uint32_t)(t - tp + 1); // first visit of idx -> plain store
      --idx;
      t = tp - 1;
    }
  }
  __syncthreads();

  if (w == 0) {
    // wave-wide inclusive scan of durations -> cum, dr, and t->x scatter map
    uint32_t d0 = dur[4 * lane], d1 = dur[4 * lane + 1];
    uint32_t d2 = dur[4 * lane + 2], d3 = dur[4 * lane + 3];
    uint32_t own = d0 + d1 + d2 + d3;
    uint32_t s = own;
#pragma unroll
    for (int off = 1; off < 64; off <<= 1) {
      uint32_t n = __shfl_up(s, off);
      if (lane >= off) s += n;
    }
    uint32_t base = s - own;
    uint32_t c0 = base + d0, c1 = c0 + d1, c2 = c1 + d2, c3 = c2 + d3;
    int x = 4 * lane;
    cum_ws[b * TX_ + x]     = (int)c0;
    cum_ws[b * TX_ + x + 1] = (int)c1;
    cum_ws[b * TX_ + x + 2] = (int)c2;
    cum_ws[b * TX_ + x + 3] = (int)c3;
    dr_out[b * TX_ + x]     = (float)d0;
    dr_out[b * TX_ + x + 1] = (float)d1;
    dr_out[b * TX_ + x + 2] = (float)d2;
    dr_out[b * TX_ + x + 3] = (float)d3;
    int* xt = xt_ws + b * TY_;
    for (uint32_t t = c0 - d0; t < c0; ++t) xt[t] = x;
    for (uint32_t t = c1 - d1; t < c1; ++t) xt[t] = x + 1;
    for (uint32_t t = c2 - d2; t < c2; ++t) xt[t] = x + 2;
    for (uint32_t t = c3 - d3; t < c3; ++t) xt[t] = x + 3;
  }
}

// ---------------------------------------------------------------------------
// Kernel C (fused epilogue): blocks [0,TX) write attn rows from cum;
// blocks [TX,TX+H) gather o_en_ex[b,h,t] = t<ylen ? en[b,h,xt[b,t]] : 0.
// ---------------------------------------------------------------------------
__global__ __launch_bounds__(256) void k_epi(
    const int* __restrict__ cum_ws, const int* __restrict__ xt_ws,
    const float* __restrict__ en, const int* __restrict__ ylp,
    float* __restrict__ attn, float* __restrict__ oen)
{
  const int b = blockIdx.y, bx = blockIdx.x, tid = threadIdx.x;
  __shared__ float row[TX_];
  if (bx < TX_) {
    const int x = bx;
    int hi = cum_ws[b * TX_ + x];
    int lo = (x > 0) ? cum_ws[b * TX_ + x - 1] : 0;
    int t0 = tid * 4;
    float4 v;
    v.x = (t0     >= lo && t0     < hi) ? 1.f : 0.f;
    v.y = (t0 + 1 >= lo && t0 + 1 < hi) ? 1.f : 0.f;
    v.z = (t0 + 2 >= lo && t0 + 2 < hi) ? 1.f : 0.f;
    v.w = (t0 + 3 >= lo && t0 + 3 < hi) ? 1.f : 0.f;
    *(float4*)&attn[((size_t)(b * TX_ + x)) * TY_ + t0] = v;
  } else {
    const int h = bx - TX_;
    row[tid] = en[((size_t)(b * H_ + h)) * TX_ + tid];
    __syncthreads();
    const int ylen = ylp[b];
    int t0 = tid * 4;
    int4 xi = *(const int4*)&xt_ws[b * TY_ + t0];
    float4 v;
    v.x = (t0     < ylen) ? row[xi.x & (TX_ - 1)] : 0.f;
    v.y = (t0 + 1 < ylen) ? row[xi.y & (TX_ - 1)] : 0.f;
    v.z = (t0 + 2 < ylen) ? row[xi.z & (TX_ - 1)] : 0.f;
    v.w = (t0 + 3 < ylen) ? row[xi.w & (TX_ - 1)] : 0.f;
    *(float4*)&oen[((size_t)(b * H_ + h)) * TY_ + t0] = v;
  }
}

extern "C" void kernel_launch(void* const* d_in, const int* in_sizes, int n_in,
                              void* d_out, int out_size, void* d_ws, size_t ws_size,
                              hipStream_t stream)
{
  const float* en = (const float*)d_in[0];
  const float* mu = (const float*)d_in[1];
  const float* ls = (const float*)d_in[2];
  const float* y  = (const float*)d_in[3];
  const int*   xl = (const int*)d_in[4];
  const int*   yl = (const int*)d_in[5];

  float* out  = (float*)d_out;
  float* oen  = out;             // [B,H,TY]
  float* logp = out + OFF_LOGP;  // [B,TX,TY]
  float* attn = out + OFF_ATTN;  // [B,TX,TY] (doubles as lpT scratch first)
  float* dr   = out + OFF_DR;    // [B,TX]

  int* cum = (int*)d_ws;               // B*TX ints
  int* xt  = cum + B_ * TX_;           // B*TY ints

  k_logp<<<dim3(TX_ / 4, B_),   256, 0, stream>>>(mu, ls, y, xl, yl, logp, attn);
  k_dp  <<<B_,                  256, 0, stream>>>(attn, xl, yl, dr, cum, xt);
  k_epi <<<dim3(TX_ + H_, B_),  256, 0, stream>>>(cum, xt, en, yl, attn, oen);
}